// Round 6
// baseline (818.232 us; speedup 1.0000x reference)
//
#include <hip/hip_runtime.h>
#include <hip/hip_fp16.h>
#include <math.h>

#define TAU_INV 5.0f   // 1 / 0.2

// ---------------------------------------------------------------------------
__device__ __forceinline__ void atomicMaxFloat(float* addr, float val) {
    if (val >= 0.0f) {
        atomicMax((int*)addr, __float_as_int(val));
    } else {
        atomicMin((unsigned int*)addr, __float_as_uint(val));
    }
}

__global__ void init_seg(float* __restrict__ seg_max, float* __restrict__ seg_sum, int n) {
    int i = blockIdx.x * blockDim.x + threadIdx.x;
    if (i < n) {
        seg_max[i] = -INFINITY;
        seg_sum[i] = 0.0f;
    }
}

// ---------------------------------------------------------------------------
// Merged fp32 GEMM, software-pipelined, BK=32, 8 rounds.
// X = [Xu; Xi] (75000 x 256); Q = X@Wq+bq, K = X@Wk+bk.
// Per round: regs->LDS, barrier, issue NEXT round's global loads into regs,
// compute 32 kk (covers the load latency), barrier.
// Epilogue: fp16 INTERLEAVED rows  QK[gr*256 + 0..127] = Q, [128..255] = K.
// ---------------------------------------------------------------------------
__global__ __launch_bounds__(256) void gemm_qk_pipe(
    const float* __restrict__ Xu, const float* __restrict__ Xi,
    const float* __restrict__ Wq, const float* __restrict__ bq,
    const float* __restrict__ Wk, const float* __restrict__ bk,
    __half* __restrict__ QK,
    int U, int I)
{
    __shared__ float As_t[32][68];    // [k][row], 8.7 KB
    __shared__ float Bs_q[32][132];   // [k][col], 16.9 KB
    __shared__ float Bs_k[32][132];

    const int tid  = threadIdx.x;
    const int row0 = blockIdx.x * 64;
    const int NT   = U + I;

    // A staging: 64 rows x 32 k = 512 float4, 2/thread
    const int ar0 = tid >> 3;              // 0..31  (idx = tid     -> rows 0..31)
    const int ar1 = (tid + 256) >> 3;      // 32..63
    const int akq = (tid & 7) * 4;         // 0..28
    // B staging: 32 k x 128 cols = 1024 float4 per matrix, 4/thread
    // t-th: idx = tid + t*256; rk = idx>>5 (0..31), c4 = (idx&31)*4

    float4 a_pre[2], bq_pre[4], bk_pre[4];

#define LOAD_TILES(K0)                                                        \
    {                                                                         \
        int gr0 = row0 + ar0;                                                 \
        int gr1 = row0 + ar1;                                                 \
        a_pre[0] = make_float4(0.f, 0.f, 0.f, 0.f);                           \
        a_pre[1] = make_float4(0.f, 0.f, 0.f, 0.f);                           \
        if (gr0 < U)          a_pre[0] = *(const float4*)&Xu[(size_t)gr0 * 256 + (K0) + akq]; \
        else if (gr0 < NT)    a_pre[0] = *(const float4*)&Xi[(size_t)(gr0 - U) * 256 + (K0) + akq]; \
        if (gr1 < U)          a_pre[1] = *(const float4*)&Xu[(size_t)gr1 * 256 + (K0) + akq]; \
        else if (gr1 < NT)    a_pre[1] = *(const float4*)&Xi[(size_t)(gr1 - U) * 256 + (K0) + akq]; \
        _Pragma("unroll")                                                     \
        for (int t = 0; t < 4; ++t) {                                         \
            int idx = tid + t * 256;                                          \
            int rk  = idx >> 5;                                               \
            int c4  = (idx & 31) * 4;                                         \
            bq_pre[t] = *(const float4*)&Wq[(size_t)((K0) + rk) * 128 + c4];  \
            bk_pre[t] = *(const float4*)&Wk[(size_t)((K0) + rk) * 128 + c4];  \
        }                                                                     \
    }

    const int tr = tid >> 5;
    const int tc = tid & 31;

    float4 accq[8], acck[8];
#pragma unroll
    for (int i = 0; i < 8; ++i) {
        accq[i] = make_float4(0.f, 0.f, 0.f, 0.f);
        acck[i] = make_float4(0.f, 0.f, 0.f, 0.f);
    }

    LOAD_TILES(0)

    for (int rnd = 0; rnd < 8; ++rnd) {
        __syncthreads();   // LDS consumers of previous round done
        // regs -> LDS
        As_t[akq + 0][ar0] = a_pre[0].x;
        As_t[akq + 1][ar0] = a_pre[0].y;
        As_t[akq + 2][ar0] = a_pre[0].z;
        As_t[akq + 3][ar0] = a_pre[0].w;
        As_t[akq + 0][ar1] = a_pre[1].x;
        As_t[akq + 1][ar1] = a_pre[1].y;
        As_t[akq + 2][ar1] = a_pre[1].z;
        As_t[akq + 3][ar1] = a_pre[1].w;
#pragma unroll
        for (int t = 0; t < 4; ++t) {
            int idx = tid + t * 256;
            int rk  = idx >> 5;
            int c4  = (idx & 31) * 4;
            *(float4*)&Bs_q[rk][c4] = bq_pre[t];
            *(float4*)&Bs_k[rk][c4] = bk_pre[t];
        }
        __syncthreads();   // LDS ready

        if (rnd < 7) LOAD_TILES((rnd + 1) * 32)   // in flight during compute

#pragma unroll
        for (int kk = 0; kk < 32; ++kk) {
            float4 a0  = *(const float4*)&As_t[kk][tr * 8];
            float4 a1  = *(const float4*)&As_t[kk][tr * 8 + 4];
            float4 bqv = *(const float4*)&Bs_q[kk][tc * 4];
            float4 bkv = *(const float4*)&Bs_k[kk][tc * 4];
            float a[8] = {a0.x, a0.y, a0.z, a0.w, a1.x, a1.y, a1.z, a1.w};
#pragma unroll
            for (int i = 0; i < 8; ++i) {
                accq[i].x += a[i] * bqv.x;
                accq[i].y += a[i] * bqv.y;
                accq[i].z += a[i] * bqv.z;
                accq[i].w += a[i] * bqv.w;
                acck[i].x += a[i] * bkv.x;
                acck[i].y += a[i] * bkv.y;
                acck[i].z += a[i] * bkv.z;
                acck[i].w += a[i] * bkv.w;
            }
        }
    }
#undef LOAD_TILES

    const float4 bbq = *(const float4*)&bq[tc * 4];
    const float4 bbk = *(const float4*)&bk[tc * 4];
#pragma unroll
    for (int i = 0; i < 8; ++i) {
        int gr = row0 + tr * 8 + i;
        if (gr < NT) {
            __half2 q01 = __floats2half2_rn(accq[i].x + bbq.x, accq[i].y + bbq.y);
            __half2 q23 = __floats2half2_rn(accq[i].z + bbq.z, accq[i].w + bbq.w);
            __half2 k01 = __floats2half2_rn(acck[i].x + bbk.x, acck[i].y + bbk.y);
            __half2 k23 = __floats2half2_rn(acck[i].z + bbk.z, acck[i].w + bbk.w);
            uint2 pq, pk;
            pq.x = *(const unsigned int*)&q01;
            pq.y = *(const unsigned int*)&q23;
            pk.x = *(const unsigned int*)&k01;
            pk.y = *(const unsigned int*)&k23;
            *(uint2*)&QK[(size_t)gr * 256 + tc * 4]       = pq;   // Q half
            *(uint2*)&QK[(size_t)gr * 256 + 128 + tc * 4] = pk;   // K half
        }
    }
}

// ---------------------------------------------------------------------------
// Fused BOTH-direction edge kernel. 32 lanes per edge:
//   lanes 0-15  (g=0): w_ui = Q_user[r] . K_item[c], seg = r,     out[eid]
//   lanes 16-31 (g=1): w_iu = Q_item[c] . K_user[r], seg = U + c, out[E+eid]
// Interleaved rows: user r -> QK + r*256, item c -> QK + (U+c)*256;
// Q half at +0, K half at +128 (halves). 16 B per lane per row.
// ---------------------------------------------------------------------------
__global__ __launch_bounds__(256) void edge_w_both(
    const __half* __restrict__ QK,
    const int* __restrict__ rows, const int* __restrict__ cols,
    const float* __restrict__ noise_ui, const float* __restrict__ noise_iu,
    float* __restrict__ out, float* __restrict__ seg_max, int U, int E)
{
    const int gtid = blockIdx.x * 256 + threadIdx.x;
    const int eid  = gtid >> 5;
    if (eid >= E) return;
    const int l  = threadIdx.x & 31;
    const int g  = l >> 4;        // 0 = ui, 1 = iu
    const int hl = l & 15;

    const int r = rows[eid];
    const int c = cols[eid];
    const __half* urow = QK + (size_t)r * 256;
    const __half* irow = QK + (size_t)(U + c) * 256;
    const __half* qrow = g ? irow : urow;
    const __half* krow = g ? urow : irow;

    const uint4 qp = *(const uint4*)(qrow + hl * 8);
    const uint4 kp = *(const uint4*)(krow + 128 + hl * 8);
    const __half2* qh = (const __half2*)&qp;
    const __half2* kh = (const __half2*)&kp;

    float d = 0.0f;
#pragma unroll
    for (int t = 0; t < 4; ++t) {
        float2 a = __half22float2(qh[t]);
        float2 b = __half22float2(kh[t]);
        d += a.x * b.x + a.y * b.y;
    }
    d += __shfl_xor(d, 8);
    d += __shfl_xor(d, 4);
    d += __shfl_xor(d, 2);
    d += __shfl_xor(d, 1);

    if (hl == 0) {
        float nz = g ? noise_iu[eid] : noise_ui[eid];
        float zz = (d - __logf(-__logf(nz))) * TAU_INV;
        int s = g ? (U + c) : r;
        out[(size_t)g * E + eid] = zz;
        atomicMaxFloat(&seg_max[s], zz);
    }
}

// ---------------------------------------------------------------------------
__global__ void edge_exp2(const float* __restrict__ z,
                          const int* __restrict__ rows, const int* __restrict__ cols,
                          const float* __restrict__ seg_max,
                          float* __restrict__ seg_sum, int U, int E)
{
    int i = blockIdx.x * blockDim.x + threadIdx.x;
    if (i >= 2 * E) return;
    int s = (i < E) ? rows[i] : (U + cols[i - E]);
    atomicAdd(&seg_sum[s], __expf(z[i] - seg_max[s]));
}

__global__ void edge_norm2(float* __restrict__ zv,
                           const int* __restrict__ rows, const int* __restrict__ cols,
                           const float* __restrict__ seg_max,
                           const float* __restrict__ seg_sum, int U, int E)
{
    int i = blockIdx.x * blockDim.x + threadIdx.x;
    if (i >= 2 * E) return;
    int s = (i < E) ? rows[i] : (U + cols[i - E]);
    zv[i] = __expf(zv[i] - seg_max[s]) / seg_sum[s];
}

// ---------------------------------------------------------------------------
extern "C" void kernel_launch(void* const* d_in, const int* in_sizes, int n_in,
                              void* d_out, int out_size, void* d_ws, size_t ws_size,
                              hipStream_t stream)
{
    const float* user_embed = (const float*)d_in[0];
    const float* item_embed = (const float*)d_in[1];
    const float* Wq = (const float*)d_in[2];
    const float* bq = (const float*)d_in[3];
    const float* Wk = (const float*)d_in[4];
    const float* bk = (const float*)d_in[5];
    const int* ui_rows    = (const int*)d_in[6];
    const int* ui_cols    = (const int*)d_in[7];
    const float* noise_ui = (const float*)d_in[8];
    const float* noise_iu = (const float*)d_in[9];

    const int H = in_sizes[3];           // 128
    const int D = in_sizes[2] / H;       // 256
    const int U = in_sizes[0] / D;       // 50000
    const int I = in_sizes[1] / D;       // 25000
    const int E = in_sizes[6];           // 1600000
    (void)D;

    const int nseg = U + I;

    // workspace: QK (fp16 interleaved, (U+I) x 256) | seg_max | seg_sum
    char* wsc = (char*)d_ws;
    __half* QK = (__half*)wsc;        wsc += (size_t)nseg * 256 * sizeof(__half);
    float* seg_max = (float*)wsc;     wsc += (size_t)nseg * sizeof(float);
    float* seg_sum = (float*)wsc;     wsc += (size_t)nseg * sizeof(float);

    float* out = (float*)d_out;       // [z_ui | z_iu], in-place softmax

    init_seg<<<(nseg + 255) / 256, 256, 0, stream>>>(seg_max, seg_sum, nseg);

    const int gblocks = (nseg + 63) / 64;
    gemm_qk_pipe<<<gblocks, 256, 0, stream>>>(user_embed, item_embed,
                                              Wq, bq, Wk, bk, QK, U, I);

    const int eblocks = (int)(((long long)E * 32 + 255) / 256);
    edge_w_both<<<eblocks, 256, 0, stream>>>(QK, ui_rows, ui_cols,
                                             noise_ui, noise_iu,
                                             out, seg_max, U, E);

    const int sblocks = (2 * E + 255) / 256;
    edge_exp2<<<sblocks, 256, 0, stream>>>(out, ui_rows, ui_cols,
                                           seg_max, seg_sum, U, E);
    edge_norm2<<<sblocks, 256, 0, stream>>>(out, ui_rows, ui_cols,
                                            seg_max, seg_sum, U, E);
}

// Round 7
// 692.093 us; speedup vs baseline: 1.1823x; 1.1823x over previous
//
#include <hip/hip_runtime.h>
#include <hip/hip_fp16.h>
#include <math.h>

#define TAU_INV 5.0f   // 1 / 0.2

// ---------------------------------------------------------------------------
__device__ __forceinline__ void atomicMaxFloat(float* addr, float val) {
    if (val >= 0.0f) {
        atomicMax((int*)addr, __float_as_int(val));
    } else {
        atomicMin((unsigned int*)addr, __float_as_uint(val));
    }
}

__global__ void init_seg(float* __restrict__ seg_max, float* __restrict__ seg_sum, int n) {
    int i = blockIdx.x * blockDim.x + threadIdx.x;
    if (i < n) {
        seg_max[i] = -INFINITY;
        seg_sum[i] = 0.0f;
    }
}

// ---------------------------------------------------------------------------
// Merged fp32 GEMM (R5 structure — known 147 us; do NOT hand-pipeline: R4's
// serial register stream and R6's cross-barrier prefetch regs both lost).
// X = [Xu; Xi] (75000 x 256); Q = X@Wq+bq, K = X@Wk+bk; A staged once.
// Epilogue: fp16 INTERLEAVED rows  QK[gr*256 + 0..127] = Q, [128..255] = K.
// ---------------------------------------------------------------------------
__global__ __launch_bounds__(256) void gemm_qk_merged(
    const float* __restrict__ Xu, const float* __restrict__ Xi,
    const float* __restrict__ Wq, const float* __restrict__ bq,
    const float* __restrict__ Wk, const float* __restrict__ bk,
    __half* __restrict__ QK,
    int U, int I, int D)
{
    __shared__ float As_t[16][68];
    __shared__ float Bs_q[16][132];
    __shared__ float Bs_k[16][132];

    const int tid  = threadIdx.x;
    const int row0 = blockIdx.x * 64;
    const int tr   = tid >> 5;
    const int tc   = tid & 31;

    float4 accq[8], acck[8];
#pragma unroll
    for (int i = 0; i < 8; ++i) {
        accq[i] = make_float4(0.f, 0.f, 0.f, 0.f);
        acck[i] = make_float4(0.f, 0.f, 0.f, 0.f);
    }

    const int ar  = tid >> 2;
    const int akq = (tid & 3) * 4;

    for (int k0 = 0; k0 < D; k0 += 16) {
        {
            int gr = row0 + ar;
            float4 v = make_float4(0.f, 0.f, 0.f, 0.f);
            if (gr < U)            v = *(const float4*)&Xu[(size_t)gr * D + k0 + akq];
            else if (gr - U < I)   v = *(const float4*)&Xi[(size_t)(gr - U) * D + k0 + akq];
            As_t[akq + 0][ar] = v.x;
            As_t[akq + 1][ar] = v.y;
            As_t[akq + 2][ar] = v.z;
            As_t[akq + 3][ar] = v.w;
        }
#pragma unroll
        for (int t = 0; t < 2; ++t) {
            int idx = tid + t * 256;
            int r  = idx >> 5;
            int c4 = (idx & 31) * 4;
            float4 vq = *(const float4*)&Wq[(size_t)(k0 + r) * 128 + c4];
            float4 vk = *(const float4*)&Wk[(size_t)(k0 + r) * 128 + c4];
            *(float4*)&Bs_q[r][c4] = vq;
            *(float4*)&Bs_k[r][c4] = vk;
        }
        __syncthreads();

#pragma unroll
        for (int kk = 0; kk < 16; ++kk) {
            float4 a0  = *(const float4*)&As_t[kk][tr * 8];
            float4 a1  = *(const float4*)&As_t[kk][tr * 8 + 4];
            float4 bqv = *(const float4*)&Bs_q[kk][tc * 4];
            float4 bkv = *(const float4*)&Bs_k[kk][tc * 4];
            float a[8] = {a0.x, a0.y, a0.z, a0.w, a1.x, a1.y, a1.z, a1.w};
#pragma unroll
            for (int i = 0; i < 8; ++i) {
                accq[i].x += a[i] * bqv.x;
                accq[i].y += a[i] * bqv.y;
                accq[i].z += a[i] * bqv.z;
                accq[i].w += a[i] * bqv.w;
                acck[i].x += a[i] * bkv.x;
                acck[i].y += a[i] * bkv.y;
                acck[i].z += a[i] * bkv.z;
                acck[i].w += a[i] * bkv.w;
            }
        }
        __syncthreads();
    }

    const float4 bbq = *(const float4*)&bq[tc * 4];
    const float4 bbk = *(const float4*)&bk[tc * 4];
    const int NT = U + I;
#pragma unroll
    for (int i = 0; i < 8; ++i) {
        int gr = row0 + tr * 8 + i;
        if (gr < NT) {
            __half2 q01 = __floats2half2_rn(accq[i].x + bbq.x, accq[i].y + bbq.y);
            __half2 q23 = __floats2half2_rn(accq[i].z + bbq.z, accq[i].w + bbq.w);
            __half2 k01 = __floats2half2_rn(acck[i].x + bbk.x, acck[i].y + bbk.y);
            __half2 k23 = __floats2half2_rn(acck[i].z + bbk.z, acck[i].w + bbk.w);
            uint2 pq, pk;
            pq.x = *(const unsigned int*)&q01;
            pq.y = *(const unsigned int*)&q23;
            pk.x = *(const unsigned int*)&k01;
            pk.y = *(const unsigned int*)&k23;
            *(uint2*)&QK[(size_t)gr * 256 + tc * 4]       = pq;   // Q half
            *(uint2*)&QK[(size_t)gr * 256 + 128 + tc * 4] = pk;   // K half
        }
    }
}

// ---------------------------------------------------------------------------
// Fused BOTH-direction edge kernel. 32 lanes per edge:
//   lanes 0-15  (g=0): w_ui = Q_user[r] . K_item[c], seg = r,     out[eid]
//   lanes 16-31 (g=1): w_iu = Q_item[c] . K_user[r], seg = U + c, out[E+eid]
// ---------------------------------------------------------------------------
__global__ __launch_bounds__(256) void edge_w_both(
    const __half* __restrict__ QK,
    const int* __restrict__ rows, const int* __restrict__ cols,
    const float* __restrict__ noise_ui, const float* __restrict__ noise_iu,
    float* __restrict__ out, float* __restrict__ seg_max, int U, int E)
{
    const int gtid = blockIdx.x * 256 + threadIdx.x;
    const int eid  = gtid >> 5;
    if (eid >= E) return;
    const int l  = threadIdx.x & 31;
    const int g  = l >> 4;        // 0 = ui, 1 = iu
    const int hl = l & 15;

    const int r = rows[eid];
    const int c = cols[eid];
    const __half* urow = QK + (size_t)r * 256;
    const __half* irow = QK + (size_t)(U + c) * 256;
    const __half* qrow = g ? irow : urow;
    const __half* krow = g ? urow : irow;

    const uint4 qp = *(const uint4*)(qrow + hl * 8);
    const uint4 kp = *(const uint4*)(krow + 128 + hl * 8);
    const __half2* qh = (const __half2*)&qp;
    const __half2* kh = (const __half2*)&kp;

    float d = 0.0f;
#pragma unroll
    for (int t = 0; t < 4; ++t) {
        float2 a = __half22float2(qh[t]);
        float2 b = __half22float2(kh[t]);
        d += a.x * b.x + a.y * b.y;
    }
    d += __shfl_xor(d, 8);
    d += __shfl_xor(d, 4);
    d += __shfl_xor(d, 2);
    d += __shfl_xor(d, 1);

    if (hl == 0) {
        float nz = g ? noise_iu[eid] : noise_ui[eid];
        float zz = (d - __logf(-__logf(nz))) * TAU_INV;
        int s = g ? (U + c) : r;
        out[(size_t)g * E + eid] = zz;
        atomicMaxFloat(&seg_max[s], zz);
    }
}

// ---------------------------------------------------------------------------
// e = exp(z - max[seg]) stored in-place; atomic segment sum.
// (Storing e lets the norm pass skip the seg_max gather and the expf.)
// ---------------------------------------------------------------------------
__global__ void edge_exp2(float* __restrict__ z,
                          const int* __restrict__ rows, const int* __restrict__ cols,
                          const float* __restrict__ seg_max,
                          float* __restrict__ seg_sum, int U, int E)
{
    int i = blockIdx.x * blockDim.x + threadIdx.x;
    if (i >= 2 * E) return;
    int s = (i < E) ? rows[i] : (U + cols[i - E]);
    float e = __expf(z[i] - seg_max[s]);
    z[i] = e;
    atomicAdd(&seg_sum[s], e);
}

// ---------------------------------------------------------------------------
// out = e / sum[seg]
// ---------------------------------------------------------------------------
__global__ void edge_norm2(float* __restrict__ ev,
                           const int* __restrict__ rows, const int* __restrict__ cols,
                           const float* __restrict__ seg_sum, int U, int E)
{
    int i = blockIdx.x * blockDim.x + threadIdx.x;
    if (i >= 2 * E) return;
    int s = (i < E) ? rows[i] : (U + cols[i - E]);
    ev[i] = ev[i] / seg_sum[s];
}

// ---------------------------------------------------------------------------
extern "C" void kernel_launch(void* const* d_in, const int* in_sizes, int n_in,
                              void* d_out, int out_size, void* d_ws, size_t ws_size,
                              hipStream_t stream)
{
    const float* user_embed = (const float*)d_in[0];
    const float* item_embed = (const float*)d_in[1];
    const float* Wq = (const float*)d_in[2];
    const float* bq = (const float*)d_in[3];
    const float* Wk = (const float*)d_in[4];
    const float* bk = (const float*)d_in[5];
    const int* ui_rows    = (const int*)d_in[6];
    const int* ui_cols    = (const int*)d_in[7];
    const float* noise_ui = (const float*)d_in[8];
    const float* noise_iu = (const float*)d_in[9];

    const int H = in_sizes[3];           // 128
    const int D = in_sizes[2] / H;       // 256
    const int U = in_sizes[0] / D;       // 50000
    const int I = in_sizes[1] / D;       // 25000
    const int E = in_sizes[6];           // 1600000

    const int nseg = U + I;

    // workspace: QK (fp16 interleaved, (U+I) x 256) | seg_max | seg_sum
    char* wsc = (char*)d_ws;
    __half* QK = (__half*)wsc;        wsc += (size_t)nseg * 256 * sizeof(__half);
    float* seg_max = (float*)wsc;     wsc += (size_t)nseg * sizeof(float);
    float* seg_sum = (float*)wsc;     wsc += (size_t)nseg * sizeof(float);

    float* out = (float*)d_out;       // [z_ui | z_iu] -> e -> normalized, in place

    init_seg<<<(nseg + 255) / 256, 256, 0, stream>>>(seg_max, seg_sum, nseg);

    const int gblocks = (nseg + 63) / 64;
    gemm_qk_merged<<<gblocks, 256, 0, stream>>>(user_embed, item_embed,
                                                Wq, bq, Wk, bk, QK, U, I, D);

    const int eblocks = (int)(((long long)E * 32 + 255) / 256);
    edge_w_both<<<eblocks, 256, 0, stream>>>(QK, ui_rows, ui_cols,
                                             noise_ui, noise_iu,
                                             out, seg_max, U, E);

    const int sblocks = (2 * E + 255) / 256;
    edge_exp2<<<sblocks, 256, 0, stream>>>(out, ui_rows, ui_cols,
                                           seg_max, seg_sum, U, E);
    edge_norm2<<<sblocks, 256, 0, stream>>>(out, ui_rows, ui_cols,
                                            seg_sum, U, E);
}